// Round 1
// baseline (32.660 us; speedup 1.0000x reference)
//
#include <hip/hip_runtime.h>

// CRF-RNN 1-D message passing, fused temporal-blocking kernel.
// B=16, N=100000, K=11 (HALF=5), 5 Jacobi iterations.
// Each block: chunk of C outputs + halo R=25 each side; all iterations in LDS.

constexpr int BLK   = 256;
constexpr int C     = 1024;          // output chunk per block
constexpr int HALF_ = 5;             // neighbor radius
constexpr int NITER = 5;
constexpr int R     = HALF_ * NITER; // 25: total halo
constexpr int E     = C + 2 * R;     // 1074: extended (q/w/unary) extent
constexpr int FE    = E + HALF_;     // 1079: feature extent (upper nbrs only)
constexpr int NPT   = (E + BLK - 1) / BLK; // 5 positions per thread
constexpr float EPS = 1e-8f;

__device__ __forceinline__ float frcp(float x) { return __builtin_amdgcn_rcpf(x); }
__device__ __forceinline__ float sigm(float x) { return frcp(1.0f + __expf(-x)); }

__global__ __launch_bounds__(BLK, 3) void crf_kernel(
    const float* __restrict__ logits, const float* __restrict__ p,
    float* __restrict__ out, int N, int chunks_per_b)
{
  __shared__ float s_feat[3][FE];   // feature channels, ext range [s-R, s-R+FE)
  __shared__ float s_wp[HALF_][E];  // s_wp[d][e] = w(e, e+d+1) * mask
  __shared__ float s_q[2][E];       // double-buffered q

  const int b     = blockIdx.x / chunks_per_b;
  const int chunk = blockIdx.x % chunks_per_b;
  const int s     = chunk * C;      // global start of output chunk
  const int tid   = threadIdx.x;
  const float* lg = logits + (size_t)b * N;
  const float* pp = p + (size_t)b * N * 3;

  // ---- load features (ext global range [s-R, s-R+FE)), clamped ----
  for (int e = tid; e < FE; e += BLK) {
    int g  = s - R + e;
    int gc = min(max(g, 0), N - 1);
    const float* src = pp + (size_t)gc * 3;
    s_feat[0][e] = src[0];
    s_feat[1][e] = src[1];
    s_feat[2][e] = src[2];
  }

  // ---- unary into regs, q0 = sigmoid(unary) into LDS ----
  float un[NPT];
  #pragma unroll
  for (int k = 0; k < NPT; ++k) {
    int e = tid + k * BLK;
    if (e < E) {
      int g  = s - R + e;
      int gc = min(max(g, 0), N - 1);
      float u = lg[gc];
      un[k] = u;
      s_q[0][e] = sigm(u);
    } else {
      un[k] = 0.0f;
    }
  }
  __syncthreads();

  // ---- pairwise weights (upper half only; symmetric) ----
  #pragma unroll
  for (int k = 0; k < NPT; ++k) {
    int e = tid + k * BLK;
    if (e < E) {
      int g = s - R + e;
      float f0 = s_feat[0][e], f1 = s_feat[1][e], f2 = s_feat[2][e];
      #pragma unroll
      for (int d = 0; d < HALF_; ++d) {
        int j = e + d + 1;              // <= E-1+5 = FE-1, in range
        float d0 = f0 - s_feat[0][j];
        float d1 = f1 - s_feat[1][j];
        float d2 = f2 - s_feat[2][j];
        float ex = __expf(-0.5f * (d0*d0 + d1*d1 + d2*d2));
        bool valid = (g >= 0) && (g + d + 1 < N);  // both endpoints in [0,N)
        s_wp[d][e] = valid ? ex : 0.0f;
      }
    }
  }
  __syncthreads();

  // ---- register-cache weights + 1/wsum per owned position ----
  float wu[NPT][HALF_], wd[NPT][HALF_], inv_ws[NPT];
  #pragma unroll
  for (int k = 0; k < NPT; ++k) {
    int e = tid + k * BLK;
    float wsum = EPS;
    #pragma unroll
    for (int d = 0; d < HALF_; ++d) {
      float a = 0.0f, bb = 0.0f;
      if (e < E) {
        a = s_wp[d][e];                       // weight to e+d+1
        int el = e - (d + 1);                 // weight to e-d-1 (symmetry)
        bb = (el >= 0) ? s_wp[d][el] : 0.0f;
      }
      wu[k][d] = a;
      wd[k][d] = bb;
      wsum += a + bb;
    }
    inv_ws[k] = frcp(wsum);
  }

  // ---- 5 Jacobi iterations, all in LDS ----
  int cur = 0;
  for (int it = 0; it < NITER; ++it) {
    #pragma unroll
    for (int k = 0; k < NPT; ++k) {
      int e = tid + k * BLK;
      if (e < E) {
        float msg = 0.0f;
        #pragma unroll
        for (int d = 0; d < HALF_; ++d) {
          int eu = e + d + 1; eu = (eu < E) ? eu : (E - 1);  // clamp: garbage zone only
          int el = e - d - 1; el = (el >= 0) ? el : 0;
          msg += wu[k][d] * s_q[cur][eu];
          msg += wd[k][d] * s_q[cur][el];
        }
        s_q[cur ^ 1][e] = sigm(un[k] + msg * inv_ws[k]);
      }
    }
    __syncthreads();
    cur ^= 1;
  }

  // ---- write final q for the owned chunk ----
  for (int e0 = tid; e0 < C; e0 += BLK) {
    int g = s + e0;
    if (g < N) out[(size_t)b * N + g] = s_q[cur][R + e0];
  }
}

extern "C" void kernel_launch(void* const* d_in, const int* in_sizes, int n_in,
                              void* d_out, int out_size, void* d_ws, size_t ws_size,
                              hipStream_t stream) {
  const float* logits = (const float*)d_in[0];
  const float* p      = (const float*)d_in[1];
  float* out          = (float*)d_out;
  const int N = 100000;
  const int B = in_sizes[0] / N;                 // 16
  const int chunks_per_b = (N + C - 1) / C;      // 98
  dim3 grid(B * chunks_per_b), block(BLK);
  crf_kernel<<<grid, block, 0, stream>>>(logits, p, out, N, chunks_per_b);
}

// Round 2
// 18.907 us; speedup vs baseline: 1.7275x; 1.7275x over previous
//
#include <hip/hip_runtime.h>

// CRF-RNN 1-D message passing — register-resident version.
// B=16, N=100000, K=11 (HALF=5), 5 Jacobi iterations.
// Each thread owns G=8 consecutive positions: q, unary, normalized weights all
// in VGPRs. LDS used only for the 5-wide halo exchange (b128, XOR-swizzled).
// Weights computed per-thread from direct global feature loads (redundant exps
// are cheap; this removes all feat/weight LDS traffic).

constexpr int BLK   = 64;            // one wave per block
constexpr int G     = 8;             // positions per thread
constexpr int E     = BLK * G;       // 512 extended positions per block
constexpr int HALF_ = 5;
constexpr int NITER = 5;
constexpr int R     = HALF_ * NITER; // 25 halo each side
constexpr int C     = E - 2 * R;     // 462 outputs per block
constexpr int NSEG  = E / 4;         // 128 float4 segments
constexpr float EPS = 1e-8f;

__device__ __forceinline__ float frcp(float x) { return __builtin_amdgcn_rcpf(x); }
__device__ __forceinline__ float sigm(float x) { return frcp(1.0f + __expf(-x)); }
__device__ __forceinline__ int   swz(int seg)  { return seg ^ ((seg >> 3) & 7); }

__global__ __launch_bounds__(BLK, 3) void crf_kernel(
    const float* __restrict__ logits, const float* __restrict__ p,
    float* __restrict__ out, int N, int chunks_per_b)
{
  __shared__ float4 s_q4[NSEG];

  const int b     = blockIdx.x / chunks_per_b;
  const int chunk = blockIdx.x % chunks_per_b;
  const int s0    = chunk * C - R;        // global index of ext position 0
  const int t     = threadIdx.x;
  const int base  = G * t;                // ext index of this thread's pos 0
  const int gb    = s0 + base;            // global index of own pos 0
  const float* lg = logits + (size_t)b * N;
  const float* pp = p + (size_t)b * N * 3;

  // ---- features for global positions [gb-5, gb+13), clamped reads ----
  float f[18][3];
  #pragma unroll
  for (int i = 0; i < 18; ++i) {
    int g  = gb + i - 5;
    int gc = min(max(g, 0), N - 1);
    const float* src = pp + 3 * (size_t)gc;
    f[i][0] = src[0]; f[i][1] = src[1]; f[i][2] = src[2];
  }

  // ---- upper-half pairwise weights: upe[i][d] = w(e_i, e_i+d+1)*mask,
  //      e_i = base + i - 5, i in [0,13) ----
  float upe[13][5];
  #pragma unroll
  for (int i = 0; i < 13; ++i) {
    int g = gb + i - 5;
    #pragma unroll
    for (int d = 0; d < 5; ++d) {
      float d0 = f[i][0] - f[i + d + 1][0];
      float d1 = f[i][1] - f[i + d + 1][1];
      float d2 = f[i][2] - f[i + d + 1][2];
      float ex = __expf(-0.5f * (d0 * d0 + d1 * d1 + d2 * d2));
      bool valid = (g >= 0) && (g + d + 1 < N);
      upe[i][d] = valid ? ex : 0.0f;
    }
  }

  // ---- per-position normalized weights + unary + q0 (all registers) ----
  float wl[G][5], wr[G][5], un[G], q[G];
  #pragma unroll
  for (int k = 0; k < G; ++k) {
    int i = k + 5;
    float ws = EPS;
    #pragma unroll
    for (int d = 0; d < 5; ++d) ws += upe[i][d] + upe[i - d - 1][d];
    float inv = frcp(ws);
    #pragma unroll
    for (int d = 0; d < 5; ++d) {
      wr[k][d] = upe[i][d] * inv;
      wl[k][d] = upe[i - d - 1][d] * inv;
    }
    int g  = gb + k;
    int gc = min(max(g, 0), N - 1);
    float u = lg[gc];
    un[k] = u;
    q[k]  = sigm(u);
  }

  // ---- swizzled LDS segment addresses (loop-invariant) ----
  const int sgA  = swz(2 * t);
  const int sgB  = swz(2 * t + 1);
  const int sgL0 = swz(max(2 * t - 2, 0));
  const int sgL1 = swz(max(2 * t - 1, 0));
  const int sgR0 = swz(min(2 * t + 2, NSEG - 1));
  const int sgR1 = swz(min(2 * t + 3, NSEG - 1));

  // publish q0
  s_q4[sgA] = make_float4(q[0], q[1], q[2], q[3]);
  s_q4[sgB] = make_float4(q[4], q[5], q[6], q[7]);
  __syncthreads();

  // ---- 5 Jacobi iterations; only halo goes through LDS ----
  #pragma unroll
  for (int it = 0; it < NITER; ++it) {
    float4 L0 = s_q4[sgL0];
    float4 L1 = s_q4[sgL1];
    float4 R0 = s_q4[sgR0];
    float4 R1 = s_q4[sgR1];
    // qx[j] = q at ext position base + j - 5, j in [0,18)
    float qx[18];
    qx[0] = L0.w; qx[1] = L1.x; qx[2] = L1.y; qx[3] = L1.z; qx[4] = L1.w;
    #pragma unroll
    for (int k = 0; k < G; ++k) qx[5 + k] = q[k];
    qx[13] = R0.x; qx[14] = R0.y; qx[15] = R0.z; qx[16] = R0.w; qx[17] = R1.x;

    #pragma unroll
    for (int k = 0; k < G; ++k) {
      float msg = 0.0f;
      #pragma unroll
      for (int d = 0; d < 5; ++d) {
        msg += wl[k][d] * qx[5 + k - d - 1];
        msg += wr[k][d] * qx[5 + k + d + 1];
      }
      q[k] = sigm(un[k] + msg);
    }

    if (it != NITER - 1) {
      __syncthreads();  // all halo reads done before overwrite
      s_q4[sgA] = make_float4(q[0], q[1], q[2], q[3]);
      s_q4[sgB] = make_float4(q[4], q[5], q[6], q[7]);
      __syncthreads();
    }
  }

  // ---- write owned outputs (ext [R, E-R), global < N) ----
  #pragma unroll
  for (int k = 0; k < G; ++k) {
    int e = base + k;
    int g = s0 + e;
    if (e >= R && e < E - R && g < N) out[(size_t)b * N + g] = q[k];
  }
}

extern "C" void kernel_launch(void* const* d_in, const int* in_sizes, int n_in,
                              void* d_out, int out_size, void* d_ws, size_t ws_size,
                              hipStream_t stream) {
  const float* logits = (const float*)d_in[0];
  const float* p      = (const float*)d_in[1];
  float* out          = (float*)d_out;
  const int N = 100000;
  const int B = in_sizes[0] / N;                 // 16
  const int chunks_per_b = (N + C - 1) / C;      // 217
  dim3 grid(B * chunks_per_b), block(BLK);
  crf_kernel<<<grid, block, 0, stream>>>(logits, p, out, N, chunks_per_b);
}